// Round 6
// baseline (276.306 us; speedup 1.0000x reference)
//
#include <hip/hip_runtime.h>

#define LSEQ 200
#define KCAP 4

__device__ __forceinline__ void fma4(float4& a, float s, const float4& v) {
    a.x = fmaf(s, v.x, a.x); a.y = fmaf(s, v.y, a.y);
    a.z = fmaf(s, v.z, a.z); a.w = fmaf(s, v.w, a.w);
}

// ---------------------------------------------------------------------------
// Fully fused MIND. Key algebra: with hisP = E[his]@S,
//   caps_e[k] = sum_l W[k,l] * E[l]        (contraction in raw e-space)
//   caps_d[k] = caps_e[k] @ S              (tiny 4x64x64)
//   B[k,l]   += E[l] . (S @ caps_d[k])     (tiny projection + dot in e-space)
// so S never touches the per-l data: no precomputed P, no 25.6MB stream.
// One batch row per block; raw E rows in regs (phase B) + LDS tile (phase D).
// B logits live in registers (thread (k=wv, l=lane+64s)).
// Static LDS 64,544 B -> 2 blocks/CU; VGPR budget 256 -> no spill.
// ---------------------------------------------------------------------------
__global__ __launch_bounds__(256, 2) void mind_fused(
    const int*   __restrict__ his, const float* __restrict__ E,
    const float* __restrict__ S,   const float* __restrict__ B0,
    const float* __restrict__ W1,  const float* __restrict__ b1,
    const float* __restrict__ W2,  const float* __restrict__ b2,
    float* __restrict__ out)
{
    __shared__ __align__(16) float4 Er4[LSEQ * 17];  // 54,400 B  E row l at [l*17+j]
    __shared__ __align__(16) float  W4[LSEQ * 4];    //  3,200    W4[l*4+k]
    __shared__ __align__(16) float4 part4[16 * 16];  //  4,096    [(w*4+k)*16 + r]
    __shared__ __align__(16) float  cbuf[256];       //  1,024    ce (C1->C2), cs (C3->D); idxs overlay
    __shared__ __align__(16) float  capsL[256];      //  1,024    capsL[k*64+d]
    __shared__ __align__(16) float  caps4[64 * 4];   //  1,024    caps4[d*4+k]

    int* idxs = (int*)cbuf;                          // live only before round 0

    const int b = blockIdx.x, tid = threadIdx.x;
    const int lane = tid & 63, wv = tid >> 6;
    const int q = lane >> 4, r = lane & 15;

    for (int l = tid; l < LSEQ; l += 256) idxs[l] = his[b * LSEQ + l];
    __syncthreads();

    // B logits + masks in registers: thread (k=wv, lane) owns l = lane+64s.
    float Breg[4], msk[4];
    #pragma unroll
    for (int s = 0; s < 4; s++) {
        int l = lane + 64 * s;
        bool in = (l < LSEQ);
        Breg[s] = in ? B0[wv * LSEQ + l] : 0.f;
        msk[s]  = (in && idxs[l] != 0) ? 0.f : -3.0e38f;
    }

    // Gather raw E rows: wave wv covers l in [wv*50,+50); thread (q,r):
    // l = base+4i+q, e-chunk = r. Registers + LDS tile. Pad rows (id==0) -> 0.
    float4 hp4[13];
    const float4* E4 = (const float4*)E;
    #pragma unroll
    for (int i = 0; i < 13; i++) {
        int  l     = wv * 50 + i * 4 + q;
        bool valid = (i < 12) || (q < 2);            // 12*4+2 = 50
        int  lc    = valid ? l : (wv * 50);
        int  id    = idxs[lc];
        float4 vv  = E4[(size_t)id * 16 + r];
        if (id == 0 || !valid) vv = make_float4(0.f, 0.f, 0.f, 0.f);
        hp4[i] = vv;
        if (valid) Er4[l * 17 + r] = vv;             // stride-17 f4: conflict-free
    }
    __syncthreads();                                  // Er4 ready; idxs dead

    for (int rr = 0; rr < 3; rr++) {
        // A: masked softmax over l from register logits; k = wv.
        {
            float x0 = Breg[0] + msk[0], x1 = Breg[1] + msk[1];
            float x2 = Breg[2] + msk[2], x3 = Breg[3] + msk[3];
            float m = fmaxf(fmaxf(x0, x1), fmaxf(x2, x3));
            #pragma unroll
            for (int off = 32; off; off >>= 1) m = fmaxf(m, __shfl_xor(m, off, 64));
            float e0 = __expf(x0 - m), e1 = __expf(x1 - m);
            float e2 = __expf(x2 - m), e3 = __expf(x3 - m);
            float ssum = e0 + e1 + e2 + e3;
            #pragma unroll
            for (int off = 32; off; off >>= 1) ssum += __shfl_xor(ssum, off, 64);
            float inv = 1.f / ssum;
            W4[lane * 4 + wv]         = e0 * inv;
            W4[(lane + 64) * 4 + wv]  = e1 * inv;
            W4[(lane + 128) * 4 + wv] = e2 * inv;
            if (lane < 8) W4[(lane + 192) * 4 + wv] = e3 * inv;
        }
        __syncthreads();

        // B: caps_e partials from registers (raw-E); W4 b128 reads only.
        {
            float4 a0 = make_float4(0,0,0,0), a1 = a0, a2 = a0, a3 = a0;
            #pragma unroll
            for (int i = 0; i < 13; i++) {
                int l  = wv * 50 + i * 4 + q;
                int lc = (l < LSEQ - 1) ? l : (LSEQ - 1);
                float4 w = *(const float4*)(W4 + lc * 4);
                fma4(a0, w.x, hp4[i]); fma4(a1, w.y, hp4[i]);
                fma4(a2, w.z, hp4[i]); fma4(a3, w.w, hp4[i]);
            }
            #pragma unroll
            for (int off = 16; off <= 32; off <<= 1) {
                a0.x += __shfl_xor(a0.x, off, 64); a0.y += __shfl_xor(a0.y, off, 64);
                a0.z += __shfl_xor(a0.z, off, 64); a0.w += __shfl_xor(a0.w, off, 64);
                a1.x += __shfl_xor(a1.x, off, 64); a1.y += __shfl_xor(a1.y, off, 64);
                a1.z += __shfl_xor(a1.z, off, 64); a1.w += __shfl_xor(a1.w, off, 64);
                a2.x += __shfl_xor(a2.x, off, 64); a2.y += __shfl_xor(a2.y, off, 64);
                a2.z += __shfl_xor(a2.z, off, 64); a2.w += __shfl_xor(a2.w, off, 64);
                a3.x += __shfl_xor(a3.x, off, 64); a3.y += __shfl_xor(a3.y, off, 64);
                a3.z += __shfl_xor(a3.z, off, 64); a3.w += __shfl_xor(a3.w, off, 64);
            }
            if (q == 0) {
                part4[(wv * 4 + 0) * 16 + r] = a0;
                part4[(wv * 4 + 1) * 16 + r] = a1;
                part4[(wv * 4 + 2) * 16 + r] = a2;
                part4[(wv * 4 + 3) * 16 + r] = a3;
            }
        }
        __syncthreads();

        // C1: reduce wave partials -> caps_e; thread = (k=wv, e=lane).
        {
            const float* pf = (const float*)part4;
            float ce = pf[(0 * 4 + wv) * 64 + lane] + pf[(1 * 4 + wv) * 64 + lane]
                     + pf[(2 * 4 + wv) * 64 + lane] + pf[(3 * 4 + wv) * 64 + lane];
            cbuf[wv * 64 + lane] = ce;
        }
        __syncthreads();

        // C2: caps_d = caps_e @ S (coalesced global S, L2-hot) + squash.
        // thread = (k=wv, d=lane).
        {
            float cd = 0.f;
            #pragma unroll 4
            for (int e = 0; e < 64; e += 4) {
                float4 cc = *(const float4*)(cbuf + wv * 64 + e);  // uniform bcast
                cd = fmaf(cc.x, S[(e + 0) * 64 + lane], cd);
                cd = fmaf(cc.y, S[(e + 1) * 64 + lane], cd);
                cd = fmaf(cc.z, S[(e + 2) * 64 + lane], cd);
                cd = fmaf(cc.w, S[(e + 3) * 64 + lane], cd);
            }
            float n2 = cd * cd;
            #pragma unroll
            for (int off = 32; off; off >>= 1) n2 += __shfl_xor(n2, off, 64);
            float n  = sqrtf(n2);
            float sc = n2 / ((1.f + n2) * n + 1e-9f);
            float c  = cd * sc;
            caps4[lane * 4 + wv] = c;
            capsL[wv * 64 + lane] = c;
        }
        __syncthreads();

        if (rr < 2) {
            // C3: capsS[k][e] = S_row_e . caps[k]  (S rows b128, L1-hot).
            // thread = (k=wv, e=lane).
            {
                const float4* S4 = (const float4*)S;
                float cs = 0.f;
                #pragma unroll
                for (int j = 0; j < 16; j++) {
                    float4 sv = S4[(size_t)lane * 16 + j];
                    float4 cv = *(const float4*)(capsL + wv * 64 + j * 4);
                    cs = fmaf(sv.x, cv.x, fmaf(sv.y, cv.y,
                         fmaf(sv.z, cv.z, fmaf(sv.w, cv.w, cs))));
                }
                cbuf[wv * 64 + lane] = cs;
            }
            __syncthreads();

            // D: B[k][l] += E[l] . capsS[k]; thread updates its OWN B slots.
            #pragma unroll
            for (int s = 0; s < 4; s++) {
                int l = lane + 64 * s;
                if (l < LSEQ) {
                    float dsum = 0.f;
                    #pragma unroll
                    for (int j = 0; j < 16; j++) {
                        float4 ev = Er4[l * 17 + j];                        // conflict-free
                        float4 cv = *(const float4*)(cbuf + wv * 64 + j * 4); // bcast
                        dsum = fmaf(ev.x, cv.x, fmaf(ev.y, cv.y,
                               fmaf(ev.z, cv.z, fmaf(ev.w, cv.w, dsum))));
                    }
                    Breg[s] += dsum;
                }
            }
            // no barrier needed: next phase A touches only regs + W4 (own slot)
        }
    }

    // MLP layer 1: thread = f; Er4 dead -> overlay h as float4 per f.
    float4* h44 = (float4*)Er4;
    {
        const int f = tid;
        float h0 = 0, h1 = 0, h2 = 0, h3 = 0;
        #pragma unroll 8
        for (int d = 0; d < 64; d++) {
            float  w = W1[d * 256 + f];                  // coalesced, L2-hot
            float4 c = *(const float4*)(caps4 + d * 4);  // b128 broadcast
            h0 = fmaf(c.x, w, h0); h1 = fmaf(c.y, w, h1);
            h2 = fmaf(c.z, w, h2); h3 = fmaf(c.w, w, h3);
        }
        float bb = b1[f];
        h44[f] = make_float4(fmaxf(h0 + bb, 0.f), fmaxf(h1 + bb, 0.f),
                             fmaxf(h2 + bb, 0.f), fmaxf(h3 + bb, 0.f));
    }
    __syncthreads();
    float* partf = (float*)part4;                        // 1024 floats exactly
    {
        float o0 = 0, o1 = 0, o2 = 0, o3 = 0;
        #pragma unroll 8
        for (int i = 0; i < 64; i++) {
            int f = wv * 64 + i;
            float  w  = W2[f * 64 + lane];               // coalesced, L2-hot
            float4 hv = h44[f];                          // b128 broadcast
            o0 = fmaf(hv.x, w, o0); o1 = fmaf(hv.y, w, o1);
            o2 = fmaf(hv.z, w, o2); o3 = fmaf(hv.w, w, o3);
        }
        partf[wv * 256 + lane]       = o0;
        partf[wv * 256 + 64 + lane]  = o1;
        partf[wv * 256 + 128 + lane] = o2;
        partf[wv * 256 + 192 + lane] = o3;
    }
    __syncthreads();
    {
        float o = partf[wv * 64 + lane]       + partf[256 + wv * 64 + lane]
                + partf[512 + wv * 64 + lane] + partf[768 + wv * 64 + lane];
        out[b * 256 + tid] = o + b2[lane];
    }
}

extern "C" void kernel_launch(void* const* d_in, const int* in_sizes, int n_in,
                              void* d_out, int out_size, void* d_ws, size_t ws_size,
                              hipStream_t stream) {
    const int*   his = (const int*)  d_in[0];
    const float* E   = (const float*)d_in[1];
    const float* S   = (const float*)d_in[2];
    const float* B0  = (const float*)d_in[3];
    const float* W1  = (const float*)d_in[4];
    const float* b1  = (const float*)d_in[5];
    const float* W2  = (const float*)d_in[6];
    const float* b2  = (const float*)d_in[7];
    float* out = (float*)d_out;
    (void)d_ws; (void)ws_size;

    mind_fused<<<4096, 256, 0, stream>>>(his, E, S, B0, W1, b1, W2, b2, out);
}